// Round 1
// baseline (108.397 us; speedup 1.0000x reference)
//
#include <hip/hip_runtime.h>

// DGCLoss: 1 - mean NDCG over 384 rows.
// N=384 rows, D=256 features, M=N-1=383 off-diagonal columns.
// Block n computes row n's full ndcg contribution.

#define NN 384
#define DD 256
#define MM 383

__global__ __launch_bounds__(384) void dgc_main(const float* __restrict__ x,
                                                const int* __restrict__ gt,
                                                float* __restrict__ acc) {
    __shared__ float xs[DD];       // row n
    __shared__ float smrow[NN];    // full similarity row (incl. diagonal col)
    __shared__ float s_cn;
    __shared__ int   hist[6];
    __shared__ int   cum[6];
    __shared__ float redA[6];
    __shared__ float redB[6];

    const int n    = blockIdx.x;
    const int t    = threadIdx.x;
    const int lane = t & 63;
    const int wave = t >> 6;

    // ---- load x_n into LDS (float4) ----
    if (t < DD / 4) {
        ((float4*)xs)[t] = ((const float4*)(x + (size_t)n * DD))[t];
    }
    if (t < 6) hist[t] = 0;
    __syncthreads();

    // ---- norm of row n ----
    float v = (t < DD) ? xs[t] * xs[t] : 0.0f;
    #pragma unroll
    for (int off = 32; off > 0; off >>= 1) v += __shfl_down(v, off, 64);
    if (lane == 0) redA[wave] = v;
    __syncthreads();
    if (t == 0) {
        float s = 0.0f;
        for (int w = 0; w < 6; ++w) s += redA[w];
        s_cn = fmaxf(sqrtf(s), 1e-8f);
    }
    __syncthreads();
    const float cn = s_cn;

    // ---- phase 2: similarity of row n with row j = t ----
    {
        const float4* xj = (const float4*)(x + (size_t)t * DD);
        const float4* xa = (const float4*)xs;
        float dot = 0.0f, ss = 0.0f;
        #pragma unroll 8
        for (int k = 0; k < DD / 4; ++k) {
            float4 b = xj[k];
            float4 a = xa[k];
            dot += a.x * b.x + a.y * b.y + a.z * b.z + a.w * b.w;
            ss  += b.x * b.x + b.y * b.y + b.z * b.z + b.w * b.w;
        }
        float cj = fmaxf(sqrtf(ss), 1e-8f);
        smrow[t] = (dot / (cn * cj) + 1.0f) * 0.5f;
    }
    __syncthreads();

    // ---- phase 3: indicator sum + dcg term (one i per thread) ----
    float dcg_c = 0.0f, idcg_c = 0.0f;
    if (t < MM) {
        const int   col = t + (t >= n ? 1 : 0);   // off-diag column index
        const float ri  = smrow[col];
        float total = 0.0f;
        for (int c = 0; c < NN; ++c) {
            float d = smrow[c] - ri;
            float a = fminf(fmaxf(d * -1000.0f, -50.0f), 50.0f);
            float e = __expf(a);
            total += __builtin_amdgcn_rcpf(1.0f + e);
        }
        // remove the diagonal column c == n (computed with identical formula)
        {
            float d = smrow[n] - ri;
            float a = fminf(fmaxf(d * -1000.0f, -50.0f), 50.0f);
            float e = __expf(a);
            total -= __builtin_amdgcn_rcpf(1.0f + e);
        }
        // self term (c == col) is exactly 0.5: ind = 1 + (total - 0.5)
        float ind = 0.5f + total;

        int gd = gt[col] - gt[n];
        int gi = gd < 0 ? -gd : gd;               // 0..5
        float rel = (float)((1 << (10 - gi)) - 1);
        dcg_c = rel / __log2f(ind + 1.0f);
        atomicAdd(&hist[gi], 1);
    }
    __syncthreads();

    // ---- idcg via histogram (relevance descending == g ascending) ----
    if (t == 0) {
        int s = 0;
        for (int g = 0; g < 6; ++g) { s += hist[g]; cum[g] = s; }
    }
    __syncthreads();
    if (t < MM) {
        int p = t;                 // sorted position
        int g = 0;
        while (p >= cum[g]) ++g;   // cum[5] == 383 > p always terminates
        float rel = (float)((1 << (10 - g)) - 1);
        idcg_c = rel / __log2f((float)(p + 2));
    }

    // ---- block reduce dcg and idcg ----
    #pragma unroll
    for (int off = 32; off > 0; off >>= 1) {
        dcg_c  += __shfl_down(dcg_c,  off, 64);
        idcg_c += __shfl_down(idcg_c, off, 64);
    }
    if (lane == 0) { redA[wave] = dcg_c; redB[wave] = idcg_c; }
    __syncthreads();
    if (t == 0) {
        float dcg = 0.0f, idcg = 0.0f;
        for (int w = 0; w < 6; ++w) { dcg += redA[w]; idcg += redB[w]; }
        atomicAdd(acc, dcg / idcg);   // idcg >= 31*discount > 0 always
    }
}

__global__ void dgc_final(const float* __restrict__ acc, float* __restrict__ out) {
    out[0] = 1.0f - acc[0] / 384.0f;
}

extern "C" void kernel_launch(void* const* d_in, const int* in_sizes, int n_in,
                              void* d_out, int out_size, void* d_ws, size_t ws_size,
                              hipStream_t stream) {
    const float* ranking = (const float*)d_in[0];
    const int*   gt      = (const int*)d_in[1];
    float*       out     = (float*)d_out;
    float*       acc     = (float*)d_ws;

    hipMemsetAsync(acc, 0, sizeof(float), stream);
    dgc_main<<<NN, 384, 0, stream>>>(ranking, gt, acc);
    dgc_final<<<1, 1, 0, stream>>>(acc, out);
}

// Round 2
// 100.475 us; speedup vs baseline: 1.0789x; 1.0789x over previous
//
#include <hip/hip_runtime.h>

// DGCLoss: 1 - mean NDCG over N rows.
// N=384 rows, D=256 features, M=383 off-diagonal columns.
//
// Structure (round 2): latency/occupancy fix.
//   dgc_sim   : block n -> scaled sim row S[n][0..384) = rank*1000*log2(e),
//               idcg[n] via 6-bin histogram sort, dcg[n] = 0.
//   dgc_body  : block (grp,n) -> 64 i's (lanes) x 4 c-quarters (waves),
//               ind sums via LDS partials, atomicAdd partial dcg into dcg[n].
//               36 waves/CU vs round-1's 9.
//   dgc_final : 1 - mean(dcg/idcg).

#define NN 384
#define DD 256
#define MM 383
// 1000 * log2(e); exp(-d*1000) == exp2((rank_i - rank_j) * SCALE)
#define SCALE  1442.6950408889634f
#define HSCALE 721.3475204444817f   // SCALE/2, for fused (cos+1)*0.5*SCALE

__global__ __launch_bounds__(384) void dgc_sim(const float* __restrict__ x,
                                               const int* __restrict__ gt,
                                               float* __restrict__ S,
                                               float* __restrict__ idcg,
                                               float* __restrict__ dcg) {
    __shared__ float xs[DD];
    __shared__ float red[6];
    __shared__ float s_invn;
    __shared__ int   hist[6];
    __shared__ int   cum[6];

    const int n    = blockIdx.x;
    const int t    = threadIdx.x;
    const int lane = t & 63;
    const int wave = t >> 6;

    if (t < DD / 4) ((float4*)xs)[t] = ((const float4*)(x + (size_t)n * DD))[t];
    if (t < 6) hist[t] = 0;
    if (t == 0) dcg[n] = 0.0f;
    __syncthreads();

    // ---- inverse norm of row n ----
    float v = (t < DD) ? xs[t] * xs[t] : 0.0f;
    #pragma unroll
    for (int off = 32; off > 0; off >>= 1) v += __shfl_down(v, off, 64);
    if (lane == 0) red[wave] = v;
    __syncthreads();
    if (t == 0) {
        float s = 0.0f;
        for (int w = 0; w < 6; ++w) s += red[w];
        s_invn = __builtin_amdgcn_rsqf(fmaxf(s, 1e-16f));
    }
    __syncthreads();
    const float invn = s_invn;

    // ---- scaled similarity row: S[n][j] = ((cos+1)*0.5) * SCALE ----
    {
        const float4* xj = (const float4*)(x + (size_t)t * DD);
        const float4* xa = (const float4*)xs;
        float dot = 0.0f, ss = 0.0f;
        #pragma unroll 8
        for (int k = 0; k < DD / 4; ++k) {
            float4 b = xj[k];
            float4 a = xa[k];
            dot += a.x * b.x + a.y * b.y + a.z * b.z + a.w * b.w;
            ss  += b.x * b.x + b.y * b.y + b.z * b.z + b.w * b.w;
        }
        float cosv = dot * invn * __builtin_amdgcn_rsqf(fmaxf(ss, 1e-16f));
        S[(size_t)n * NN + t] = fmaf(cosv, HSCALE, HSCALE);
    }

    // ---- idcg[n] via histogram (relevance desc == g asc) ----
    float idcg_c = 0.0f;
    if (t < MM) {
        const int col = t + (t >= n ? 1 : 0);
        int gd = gt[col] - gt[n];
        int gi = gd < 0 ? -gd : gd;
        atomicAdd(&hist[gi], 1);
    }
    __syncthreads();
    if (t == 0) {
        int s = 0;
        for (int g = 0; g < 6; ++g) { s += hist[g]; cum[g] = s; }
    }
    __syncthreads();
    if (t < MM) {
        int p = t, g = 0;
        while (p >= cum[g]) ++g;
        float rel = (float)((1 << (10 - g)) - 1);
        idcg_c = rel / __log2f((float)(p + 2));
    }
    #pragma unroll
    for (int off = 32; off > 0; off >>= 1) idcg_c += __shfl_down(idcg_c, off, 64);
    if (lane == 0) red[wave] = idcg_c;
    __syncthreads();
    if (t == 0) {
        float s = 0.0f;
        for (int w = 0; w < 6; ++w) s += red[w];
        idcg[n] = s;
    }
}

__global__ __launch_bounds__(256) void dgc_body(const float* __restrict__ S,
                                                const int* __restrict__ gt,
                                                float* __restrict__ dcg) {
    __shared__ float srow[NN];
    __shared__ float part[4][64];

    const int grp  = blockIdx.x;   // 0..5
    const int n    = blockIdx.y;   // 0..383
    const int t    = threadIdx.x;
    const int lane = t & 63;
    const int w    = t >> 6;       // c-quarter

    if (t < NN / 4) ((float4*)srow)[t] = ((const float4*)(S + (size_t)n * NN))[t];
    __syncthreads();

    const int  i_off = grp * 64 + lane;      // off-diag row index, 0..382 valid
    const bool valid = i_off < MM;
    const int  col   = valid ? i_off + (i_off >= n ? 1 : 0) : 0;
    const float ri   = srow[col];

    // sum sigma over 96 columns c: term = 1/(1 + 2^(ri - s_c))
    float partial = 0.0f;
    const int c0 = w * 96;
    #pragma unroll 8
    for (int c = c0; c < c0 + 96; ++c) {
        partial += __builtin_amdgcn_rcpf(1.0f + exp2f(ri - srow[c]));
    }
    // remove diagonal column c == n if it fell in this quarter (wave-uniform)
    if (n >= c0 && n < c0 + 96) {
        partial -= __builtin_amdgcn_rcpf(1.0f + exp2f(ri - srow[n]));
    }
    part[w][lane] = partial;
    __syncthreads();

    if (w == 0) {
        // self term (c == col) was exactly 0.5: ind = 1 + (sum - 0.5)
        float ind = part[0][lane] + part[1][lane] + part[2][lane] + part[3][lane] + 0.5f;
        float dcg_i = 0.0f;
        if (valid) {
            int gd = gt[col] - gt[n];
            int gi = gd < 0 ? -gd : gd;
            float rel = (float)((1 << (10 - gi)) - 1);
            dcg_i = rel / __log2f(ind + 1.0f);
        }
        #pragma unroll
        for (int off = 32; off > 0; off >>= 1) dcg_i += __shfl_down(dcg_i, off, 64);
        if (lane == 0) atomicAdd(&dcg[n], dcg_i);
    }
}

__global__ __launch_bounds__(384) void dgc_final(const float* __restrict__ dcg,
                                                 const float* __restrict__ idcg,
                                                 float* __restrict__ out) {
    __shared__ float red[6];
    const int t    = threadIdx.x;
    const int lane = t & 63;
    const int wave = t >> 6;
    float nd = dcg[t] / idcg[t];   // idcg >= 31 always (rel_min=31, discount 1)
    #pragma unroll
    for (int off = 32; off > 0; off >>= 1) nd += __shfl_down(nd, off, 64);
    if (lane == 0) red[wave] = nd;
    __syncthreads();
    if (t == 0) {
        float s = 0.0f;
        for (int w = 0; w < 6; ++w) s += red[w];
        out[0] = 1.0f - s / (float)NN;
    }
}

extern "C" void kernel_launch(void* const* d_in, const int* in_sizes, int n_in,
                              void* d_out, int out_size, void* d_ws, size_t ws_size,
                              hipStream_t stream) {
    const float* ranking = (const float*)d_in[0];
    const int*   gt      = (const int*)d_in[1];
    float*       out     = (float*)d_out;

    float* S    = (float*)d_ws;           // 384*384 floats
    float* idcg = S + (size_t)NN * NN;    // 384 floats
    float* dcg  = idcg + NN;              // 384 floats

    dgc_sim<<<NN, 384, 0, stream>>>(ranking, gt, S, idcg, dcg);
    dgc_body<<<dim3(6, NN), 256, 0, stream>>>(S, gt, dcg);
    dgc_final<<<1, 384, 0, stream>>>(dcg, idcg, out);
}